// Round 5
// baseline (347.306 us; speedup 1.0000x reference)
//
#include <hip/hip_runtime.h>
#include <hip/hip_bf16.h>
#include <stdint.h>

typedef int i32x4 __attribute__((ext_vector_type(4)));
typedef int i32x16 __attribute__((ext_vector_type(16)));

#define K_DIM 2048
#define M_DIM 8192   // B*S = 4*2048 tokens
#define N_DIM 8192   // D_OUT
#define QBF   127.0f
#define EPSF  1e-5f
#define NT    64     // K_DIM / 32 sub-tiles (BK=32)

__device__ __forceinline__ void load_lds16(const void* gsrc, void* ldst) {
    __builtin_amdgcn_global_load_lds(
        (__attribute__((address_space(1))) void*)gsrc,
        (__attribute__((address_space(3))) void*)ldst,
        16, 0, 0);
}

// ---------- Kernel 1: deterministic partial |W| sums ----------
__global__ __launch_bounds__(256) void k_abs_partial(const float* __restrict__ w,
                                                     float* __restrict__ partial) {
    __shared__ float red[256];
    int t = threadIdx.x, b = blockIdx.x;
    const float4* w4 = (const float4*)w;
    size_t base = (size_t)b * 2048;
    float s = 0.f;
#pragma unroll
    for (int j = 0; j < 8; ++j) {
        float4 v = w4[base + j * 256 + t];
        s += fabsf(v.x) + fabsf(v.y) + fabsf(v.z) + fabsf(v.w);
    }
    red[t] = s; __syncthreads();
    for (int off = 128; off > 0; off >>= 1) {
        if (t < off) red[t] += red[t + off];
        __syncthreads();
    }
    if (t == 0) partial[b] = red[0];
}

// ---------- Kernel 2: gamma = sum(partial)/count ----------
__global__ __launch_bounds__(256) void k_gamma(const float* __restrict__ partial,
                                               float* __restrict__ gamma) {
    __shared__ float red[256];
    int t = threadIdx.x;
    float s = 0.f;
#pragma unroll
    for (int j = 0; j < 8; ++j) s += partial[t + j * 256];
    red[t] = s; __syncthreads();
    for (int off = 128; off > 0; off >>= 1) {
        if (t < off) red[t] += red[t + off];
        __syncthreads();
    }
    if (t == 0) gamma[0] = red[0] / 16777216.0f;
}

// ---------- Kernel 3: ternary-quantize W -> int8 ----------
__global__ __launch_bounds__(256) void k_quant_w(const float* __restrict__ w,
                                                 const float* __restrict__ gamma,
                                                 uint* __restrict__ wq) {
    float g = fmaxf(gamma[0], EPSF);
    int tid = blockIdx.x * 256 + threadIdx.x;    // 4,194,304 threads
    float4 v = ((const float4*)w)[tid];
    int a = (int)fminf(fmaxf(rintf(v.x / g), -1.f), 1.f);
    int b = (int)fminf(fmaxf(rintf(v.y / g), -1.f), 1.f);
    int c = (int)fminf(fmaxf(rintf(v.z / g), -1.f), 1.f);
    int d = (int)fminf(fmaxf(rintf(v.w / g), -1.f), 1.f);
    wq[tid] = (a & 255) | ((b & 255) << 8) | ((c & 255) << 16) | ((d & 255) << 24);
}

// ---------- Kernel 4: per-token absmax-quantize x -> int8, alpha ----------
__global__ __launch_bounds__(256) void k_quant_x(const float* __restrict__ x,
                                                 uint* __restrict__ xq,
                                                 float* __restrict__ alpha) {
    __shared__ float red[256];
    int t = threadIdx.x, row = blockIdx.x;
    const float4* x4 = (const float4*)x + (size_t)row * 512;
    float4 v0 = x4[t], v1 = x4[t + 256];
    float m = fmaxf(fmaxf(fabsf(v0.x), fabsf(v0.y)), fmaxf(fabsf(v0.z), fabsf(v0.w)));
    m = fmaxf(m, fmaxf(fmaxf(fabsf(v1.x), fabsf(v1.y)), fmaxf(fabsf(v1.z), fabsf(v1.w))));
    red[t] = m; __syncthreads();
    for (int off = 128; off > 0; off >>= 1) {
        if (t < off) red[t] = fmaxf(red[t], red[t + off]);
        __syncthreads();
    }
    float a = red[0];
    if (t == 0) alpha[row] = a;
    float den = fmaxf(a, EPSF);
    uint* q = xq + (size_t)row * 512;
    int q0 = (int)fminf(fmaxf(rintf(v0.x * QBF / den), -QBF), QBF);
    int q1 = (int)fminf(fmaxf(rintf(v0.y * QBF / den), -QBF), QBF);
    int q2 = (int)fminf(fmaxf(rintf(v0.z * QBF / den), -QBF), QBF);
    int q3 = (int)fminf(fmaxf(rintf(v0.w * QBF / den), -QBF), QBF);
    q[t] = (q0 & 255) | ((q1 & 255) << 8) | ((q2 & 255) << 16) | ((q3 & 255) << 24);
    q0 = (int)fminf(fmaxf(rintf(v1.x * QBF / den), -QBF), QBF);
    q1 = (int)fminf(fmaxf(rintf(v1.y * QBF / den), -QBF), QBF);
    q2 = (int)fminf(fmaxf(rintf(v1.z * QBF / den), -QBF), QBF);
    q3 = (int)fminf(fmaxf(rintf(v1.w * QBF / den), -QBF), QBF);
    q[t + 256] = (q0 & 255) | ((q1 & 255) << 8) | ((q2 & 255) << 16) | ((q3 & 255) << 24);
}

// ---------- Kernel 5: 128x128 i8 GEMM, 32x32x32 MFMA, 4 blocks/CU ----------
// A = xq [M,K] i8, B = wq [N,K] i8. 256 threads = 4 waves (2x2), wave owns 64x64
// (2x2 frags of 32x32, acc = 4 x i32x16 = 64 regs -> 4 waves/SIMD).
// mfma_i32_32x32x32_i8 operand: lane l holds row l&31, k-bytes (l>>5)*16..+16
// (K-doubling family pattern; C/D 32x32 layout verified m74/m101, dtype-indep).
// LDS fragment-major: frag = 64 granules of 16B, granule g = (row g&31, kc g>>5);
// read addr = frag_base + l*16 -> linear, conflict-free, NO swizzle needed.
// global_load_lds writes linearly (base + lane*16); the (row,kc) permutation
// lives in the per-lane GLOBAL source address (m173 pattern).
// Subtile = 8KB (A 4 frags + B 4 frags), 4-deep ring = 32KB -> 4 blocks/CU.
// vmcnt ledger (2 issues/wave/subtile, prefetch depth 3): top of kt -> 6 in
// flight, retire kt's 2 -> vmcnt(4); kt==NT-2 -> 2; kt==NT-1 -> 0.
// One barrier + one lgkmcnt(0) per subtile; slot-reuse hazard safe because every
// wave drains lgkmcnt(0) (its reads of slot kt-1 done) before the next top
// barrier, and staging for kt+3 (same slot) issues only after that barrier.
__global__ __launch_bounds__(256, 4) void k_gemm(const uint8_t* __restrict__ xq,
                                                 const uint8_t* __restrict__ wq,
                                                 const float* __restrict__ alpha,
                                                 const float* __restrict__ gamma,
                                                 float* __restrict__ out) {
    __shared__ __align__(16) char smem[32768];   // 4 ring slots x 8KB

    int bid = blockIdx.x;
    int wg = (bid & 7) * 512 + (bid >> 3);       // XCD-bijective (4096 % 8 == 0)
    int tm = wg >> 6, tn = wg & 63;

    int t = threadIdx.x;
    int w = t >> 6, l = t & 63;
    int wr = w >> 1, wc = w & 1;                 // 2x2 waves

    // ---- staging: wave w owns frags {2w, 2w+1}; frags 0-3 = A rows, 4-7 = B cols
    const uint8_t* srcb[2];
    int dstq[2];
#pragma unroll
    for (int j = 0; j < 2; ++j) {
        int fj = w * 2 + j;
        int isB = fj >> 2;
        int fi = fj & 3;
        int row = fi * 32 + (l & 31);            // tile-local row/col 0..127
        int kc = l >> 5;                         // 16B k-chunk 0..1
        int grow = (isB ? tn : tm) * 128 + row;
        srcb[j] = (isB ? wq : xq) + (size_t)grow * K_DIM + kc * 16;
        dstq[j] = fj * 1024;                     // + slot*8192; lane writes +l*16
    }

    i32x16 acc[2][2];
#pragma unroll
    for (int m = 0; m < 2; ++m)
#pragma unroll
        for (int n = 0; n < 2; ++n) acc[m][n] = (i32x16){0};

    int aoff[2], boff[2];
#pragma unroll
    for (int i = 0; i < 2; ++i) {
        aoff[i] = (wr * 2 + i) * 1024 + l * 16;
        boff[i] = 4096 + (wc * 2 + i) * 1024 + l * 16;
    }

    // ---- prologue: stage sub-tiles 0..2 (6 issues/wave outstanding)
#pragma unroll
    for (int p = 0; p < 3; ++p)
#pragma unroll
        for (int j = 0; j < 2; ++j)
            load_lds16(srcb[j] + (size_t)p * 32, smem + p * 8192 + dstq[j]);

    for (int kt = 0; kt < NT; ++kt) {
        char* sb = smem + (kt & 3) * 8192;
        if (kt < NT - 2)       asm volatile("s_waitcnt vmcnt(4)" ::: "memory");
        else if (kt == NT - 2) asm volatile("s_waitcnt vmcnt(2)" ::: "memory");
        else                   asm volatile("s_waitcnt vmcnt(0)" ::: "memory");
        __builtin_amdgcn_s_barrier();

        i32x4 a0 = *(const i32x4*)(sb + aoff[0]);
        i32x4 a1 = *(const i32x4*)(sb + aoff[1]);
        i32x4 b0 = *(const i32x4*)(sb + boff[0]);
        i32x4 b1 = *(const i32x4*)(sb + boff[1]);
        if (kt + 3 < NT) {                       // slot (kt+3)&3 == (kt-1)&3, freed
            char* db = smem + ((kt + 3) & 3) * 8192;
            load_lds16(srcb[0] + (size_t)(kt + 3) * 32, db + dstq[0]);
            load_lds16(srcb[1] + (size_t)(kt + 3) * 32, db + dstq[1]);
        }
        asm volatile("s_waitcnt lgkmcnt(0)" ::: "memory");
        __builtin_amdgcn_sched_barrier(0);
        __builtin_amdgcn_s_setprio(1);
        acc[0][0] = __builtin_amdgcn_mfma_i32_32x32x32_i8(a0, b0, acc[0][0], 0, 0, 0);
        acc[0][1] = __builtin_amdgcn_mfma_i32_32x32x32_i8(a0, b1, acc[0][1], 0, 0, 0);
        acc[1][0] = __builtin_amdgcn_mfma_i32_32x32x32_i8(a1, b0, acc[1][0], 0, 0, 0);
        acc[1][1] = __builtin_amdgcn_mfma_i32_32x32x32_i8(a1, b1, acc[1][1], 0, 0, 0);
        __builtin_amdgcn_s_setprio(0);
    }

    // ---- epilogue: out = (float)acc * alpha[row] * gamma / 127 ----
    // C/D 32x32: col = lane&31, row = (reg&3) + 8*(reg>>2) + 4*(lane>>5)
    float gs = gamma[0] / QBF;
    int hi = l >> 5, lc = l & 31;
#pragma unroll
    for (int mi = 0; mi < 2; ++mi) {
        int rowb = tm * 128 + wr * 64 + mi * 32 + hi * 4;
#pragma unroll
        for (int reg = 0; reg < 16; ++reg) {
            int row = rowb + (reg & 3) + 8 * (reg >> 2);
            float s = alpha[row] * gs;
            size_t rb = (size_t)row * N_DIM + tn * 128 + wc * 64 + lc;
            out[rb]      = (float)acc[mi][0][reg] * s;
            out[rb + 32] = (float)acc[mi][1][reg] * s;
        }
    }
}

extern "C" void kernel_launch(void* const* d_in, const int* in_sizes, int n_in,
                              void* d_out, int out_size, void* d_ws, size_t ws_size,
                              hipStream_t stream) {
    const float* x  = (const float*)d_in[0];   // [4,2048,2048]
    const float* wt = (const float*)d_in[1];   // [8192,2048]
    float* out = (float*)d_out;                // [4,2048,8192] fp32

    char* ws = (char*)d_ws;
    uint8_t* xq     = (uint8_t*)ws;                     // 16,777,216 B
    uint8_t* wq     = (uint8_t*)(ws + 16777216);        // 16,777,216 B
    float* alpha    = (float*)(ws + 33554432);          // 32,768 B
    float* partial  = (float*)(ws + 33587200);          // 8,192 B
    float* gamma    = (float*)(ws + 33595392);          // 4 B

    k_abs_partial<<<2048, 256, 0, stream>>>(wt, partial);
    k_gamma<<<1, 256, 0, stream>>>(partial, gamma);
    k_quant_w<<<16384, 256, 0, stream>>>(wt, gamma, (uint*)wq);
    k_quant_x<<<8192, 256, 0, stream>>>(x, (uint*)xq, alpha);
    k_gemm<<<4096, 256, 0, stream>>>(xq, wq, alpha, gamma, out);
}

// Round 6
// 228.080 us; speedup vs baseline: 1.5227x; 1.5227x over previous
//
#include <hip/hip_runtime.h>
#include <hip/hip_bf16.h>
#include <stdint.h>

typedef int i32x4 __attribute__((ext_vector_type(4)));
typedef int i32x16 __attribute__((ext_vector_type(16)));

#define K_DIM 2048
#define M_DIM 8192   // B*S = 4*2048 tokens
#define N_DIM 8192   // D_OUT
#define QBF   127.0f
#define EPSF  1e-5f
#define NT    32     // K_DIM / 64 sub-tiles (BK=64)

__device__ __forceinline__ void load_lds16(const void* gsrc, void* ldst) {
    __builtin_amdgcn_global_load_lds(
        (__attribute__((address_space(1))) void*)gsrc,
        (__attribute__((address_space(3))) void*)ldst,
        16, 0, 0);
}

// ---------- Kernel 1: deterministic partial |W| sums ----------
__global__ __launch_bounds__(256) void k_abs_partial(const float* __restrict__ w,
                                                     float* __restrict__ partial) {
    __shared__ float red[256];
    int t = threadIdx.x, b = blockIdx.x;
    const float4* w4 = (const float4*)w;
    size_t base = (size_t)b * 2048;
    float s = 0.f;
#pragma unroll
    for (int j = 0; j < 8; ++j) {
        float4 v = w4[base + j * 256 + t];
        s += fabsf(v.x) + fabsf(v.y) + fabsf(v.z) + fabsf(v.w);
    }
    red[t] = s; __syncthreads();
    for (int off = 128; off > 0; off >>= 1) {
        if (t < off) red[t] += red[t + off];
        __syncthreads();
    }
    if (t == 0) partial[b] = red[0];
}

// ---------- Kernel 2: gamma = sum(partial)/count ----------
__global__ __launch_bounds__(256) void k_gamma(const float* __restrict__ partial,
                                               float* __restrict__ gamma) {
    __shared__ float red[256];
    int t = threadIdx.x;
    float s = 0.f;
#pragma unroll
    for (int j = 0; j < 8; ++j) s += partial[t + j * 256];
    red[t] = s; __syncthreads();
    for (int off = 128; off > 0; off >>= 1) {
        if (t < off) red[t] += red[t + off];
        __syncthreads();
    }
    if (t == 0) gamma[0] = red[0] / 16777216.0f;
}

// ---------- Kernel 3: ternary-quantize W -> int8 ----------
__global__ __launch_bounds__(256) void k_quant_w(const float* __restrict__ w,
                                                 const float* __restrict__ gamma,
                                                 uint* __restrict__ wq) {
    float g = fmaxf(gamma[0], EPSF);
    int tid = blockIdx.x * 256 + threadIdx.x;    // 4,194,304 threads
    float4 v = ((const float4*)w)[tid];
    int a = (int)fminf(fmaxf(rintf(v.x / g), -1.f), 1.f);
    int b = (int)fminf(fmaxf(rintf(v.y / g), -1.f), 1.f);
    int c = (int)fminf(fmaxf(rintf(v.z / g), -1.f), 1.f);
    int d = (int)fminf(fmaxf(rintf(v.w / g), -1.f), 1.f);
    wq[tid] = (a & 255) | ((b & 255) << 8) | ((c & 255) << 16) | ((d & 255) << 24);
}

// ---------- Kernel 4: per-token absmax-quantize x -> int8, alpha ----------
__global__ __launch_bounds__(256) void k_quant_x(const float* __restrict__ x,
                                                 uint* __restrict__ xq,
                                                 float* __restrict__ alpha) {
    __shared__ float red[256];
    int t = threadIdx.x, row = blockIdx.x;
    const float4* x4 = (const float4*)x + (size_t)row * 512;
    float4 v0 = x4[t], v1 = x4[t + 256];
    float m = fmaxf(fmaxf(fabsf(v0.x), fabsf(v0.y)), fmaxf(fabsf(v0.z), fabsf(v0.w)));
    m = fmaxf(m, fmaxf(fmaxf(fabsf(v1.x), fabsf(v1.y)), fmaxf(fabsf(v1.z), fabsf(v1.w))));
    red[t] = m; __syncthreads();
    for (int off = 128; off > 0; off >>= 1) {
        if (t < off) red[t] = fmaxf(red[t], red[t + off]);
        __syncthreads();
    }
    float a = red[0];
    if (t == 0) alpha[row] = a;
    float den = fmaxf(a, EPSF);
    uint* q = xq + (size_t)row * 512;
    int q0 = (int)fminf(fmaxf(rintf(v0.x * QBF / den), -QBF), QBF);
    int q1 = (int)fminf(fmaxf(rintf(v0.y * QBF / den), -QBF), QBF);
    int q2 = (int)fminf(fmaxf(rintf(v0.z * QBF / den), -QBF), QBF);
    int q3 = (int)fminf(fmaxf(rintf(v0.w * QBF / den), -QBF), QBF);
    q[t] = (q0 & 255) | ((q1 & 255) << 8) | ((q2 & 255) << 16) | ((q3 & 255) << 24);
    q0 = (int)fminf(fmaxf(rintf(v1.x * QBF / den), -QBF), QBF);
    q1 = (int)fminf(fmaxf(rintf(v1.y * QBF / den), -QBF), QBF);
    q2 = (int)fminf(fmaxf(rintf(v1.z * QBF / den), -QBF), QBF);
    q3 = (int)fminf(fmaxf(rintf(v1.w * QBF / den), -QBF), QBF);
    q[t + 256] = (q0 & 255) | ((q1 & 255) << 8) | ((q2 & 255) << 16) | ((q3 & 255) << 24);
}

// ---------- Kernel 5: 256x256 i8 GEMM, 32x32x32 MFMA, k-split pipeline ----------
// Round-4 geometry (proven 163us): 512 thr = 8 waves (2x4), wave owns 128x64,
// BK=64 subtile (A 256x64 + B 256x64 = 32KB), 4-deep ring = 128KB, 1 block/CU.
// LDS layout + swizzle IDENTICAL to round 4 (measured 0 conflicts): row-major
// [256][64B], 4 x 16B chunks/row, phys_chunk = logical ^ ((row>>1)&3); staged by
// global_load_lds with linear dest + pre-swizzled global source.
// MFMA: mfma_i32_32x32x32_i8 (4404 TOPS vs 3944 for 16x16x64). Operand layout:
// lane l holds row l&31, k-bytes (l>>5)*16..+16 (verified by round 5 passing).
// Wave frags: 4(M) x 2(N) per k-half; acc[4][2] x i32x16 = 128 regs.
// K-split pipeline per subtile: reads(k0) | staging | reads(k1) | lgkmcnt(6) ->
// MFMA(k0) overlaps k1 reads | lgkmcnt(0) -> MFMA(k1). sched_barrier(0) pins
// preserve ds_read FIFO order so the counted lgkmcnt(6) retires exactly k0's 6.
// vmcnt ledger (4 issues/wave/subtile, depth 3): top of kt -> 12 outstanding,
// retire kt's 4 -> vmcnt(8); kt==NT-2 -> 4; kt==NT-1 -> 0. Never 0 mid-loop.
// Slot-reuse safe: every wave passes lgkmcnt(0) before next top barrier, and
// staging for kt+3 (same slot as kt-1) issues only after that barrier.
__global__ __launch_bounds__(512, 2) void k_gemm(const uint8_t* __restrict__ xq,
                                                 const uint8_t* __restrict__ wq,
                                                 const float* __restrict__ alpha,
                                                 const float* __restrict__ gamma,
                                                 float* __restrict__ out) {
    __shared__ __align__(16) char smem[131072];  // 4 ring slots x 32KB

    int bid = blockIdx.x;
    int wg = (bid & 7) * 128 + (bid >> 3);       // XCD-bijective (1024 % 8 == 0)
    int tm = wg >> 5, tn = wg & 31;

    int t = threadIdx.x;
    int w = t >> 6, l = t & 63;
    int wr = w >> 2, wc = w & 3;                 // 2x4 waves, wave tile 128x64

    // ---- staging descriptors (verbatim round 4): 4 regions/wave/subtile, 1KB each
    const uint8_t* srcb[4];
    int dstq[4];
    {
        int rsub = l >> 2;                       // row within 16-row region
        int clog = (l & 3) ^ ((rsub >> 1) & 3);  // pre-swizzled source chunk
#pragma unroll
        for (int j = 0; j < 4; ++j) {
            int q = w * 4 + j;                   // region 0..31 (0-15 A, 16-31 B)
            int isB = q >> 4;
            int r = (q & 15) * 16 + rsub;        // tile-local row 0..255
            int grow = (isB ? tn : tm) * 256 + r;
            srcb[j] = (isB ? wq : xq) + (size_t)grow * K_DIM + clog * 16;
            dstq[j] = q * 1024;                  // wave-uniform LDS offset
        }
    }

    i32x16 acc[4][2];
#pragma unroll
    for (int m = 0; m < 4; ++m)
#pragma unroll
        for (int n = 0; n < 2; ++n) acc[m][n] = (i32x16){0};

    // ---- read offsets: row = base + (l&31); logical chunk = kh*2 + (l>>5)
    int lr = l & 31, kq = l >> 5, sw = (l >> 1) & 3;
    int pk0 = (kq ^ sw) * 16;                    // phys chunk byte off, k-half 0
    int pk1 = ((2 + kq) ^ sw) * 16;              // k-half 1
    int aoff[4], boff[2];
#pragma unroll
    for (int mi = 0; mi < 4; ++mi) aoff[mi] = (wr * 128 + mi * 32 + lr) * 64;
#pragma unroll
    for (int nj = 0; nj < 2; ++nj) boff[nj] = 16384 + (wc * 64 + nj * 32 + lr) * 64;

    // ---- prologue: stage sub-tiles 0..2 (12 issues/wave outstanding)
#pragma unroll
    for (int p = 0; p < 3; ++p)
#pragma unroll
        for (int j = 0; j < 4; ++j)
            load_lds16(srcb[j] + (size_t)p * 64, smem + p * 32768 + dstq[j]);

    for (int kt = 0; kt < NT; ++kt) {
        char* sb = smem + (kt & 3) * 32768;
        if (kt < NT - 2)       asm volatile("s_waitcnt vmcnt(8)" ::: "memory");
        else if (kt == NT - 2) asm volatile("s_waitcnt vmcnt(4)" ::: "memory");
        else                   asm volatile("s_waitcnt vmcnt(0)" ::: "memory");
        __builtin_amdgcn_s_barrier();

        i32x4 a0[4], b0[2], a1[4], b1[2];
        // k-half 0 reads (the 6 oldest DS ops)
#pragma unroll
        for (int mi = 0; mi < 4; ++mi) a0[mi] = *(const i32x4*)(sb + aoff[mi] + pk0);
#pragma unroll
        for (int nj = 0; nj < 2; ++nj) b0[nj] = *(const i32x4*)(sb + boff[nj] + pk0);
        __builtin_amdgcn_sched_barrier(0);       // pin: k0 reads are oldest
        // staging for kt+3 (slot freed at last lgkmcnt(0) + this top barrier)
        if (kt + 3 < NT) {
            char* db = smem + ((kt + 3) & 3) * 32768;
#pragma unroll
            for (int j = 0; j < 4; ++j)
                load_lds16(srcb[j] + (size_t)(kt + 3) * 64, db + dstq[j]);
        }
        // k-half 1 reads (overlap k0's MFMA)
#pragma unroll
        for (int mi = 0; mi < 4; ++mi) a1[mi] = *(const i32x4*)(sb + aoff[mi] + pk1);
#pragma unroll
        for (int nj = 0; nj < 2; ++nj) b1[nj] = *(const i32x4*)(sb + boff[nj] + pk1);

        asm volatile("s_waitcnt lgkmcnt(6)" ::: "memory");  // k0's 6 retired
        __builtin_amdgcn_sched_barrier(0);
        __builtin_amdgcn_s_setprio(1);
#pragma unroll
        for (int mi = 0; mi < 4; ++mi)
#pragma unroll
            for (int nj = 0; nj < 2; ++nj)
                acc[mi][nj] = __builtin_amdgcn_mfma_i32_32x32x32_i8(
                    a0[mi], b0[nj], acc[mi][nj], 0, 0, 0);
        __builtin_amdgcn_s_setprio(0);

        asm volatile("s_waitcnt lgkmcnt(0)" ::: "memory");
        __builtin_amdgcn_sched_barrier(0);
        __builtin_amdgcn_s_setprio(1);
#pragma unroll
        for (int mi = 0; mi < 4; ++mi)
#pragma unroll
            for (int nj = 0; nj < 2; ++nj)
                acc[mi][nj] = __builtin_amdgcn_mfma_i32_32x32x32_i8(
                    a1[mi], b1[nj], acc[mi][nj], 0, 0, 0);
        __builtin_amdgcn_s_setprio(0);
    }

    // ---- epilogue: out = (float)acc * alpha[row] * gamma / 127 ----
    // C/D 32x32: col = lane&31, row = (reg&3) + 8*(reg>>2) + 4*(lane>>5)
    float gs = gamma[0] / QBF;
    int hi4 = (l >> 5) * 4, lc = l & 31;
#pragma unroll
    for (int mi = 0; mi < 4; ++mi) {
        int rowb = tm * 256 + wr * 128 + mi * 32 + hi4;
#pragma unroll
        for (int reg = 0; reg < 16; ++reg) {
            int row = rowb + (reg & 3) + 8 * (reg >> 2);
            float s = alpha[row] * gs;
            size_t rb = (size_t)row * N_DIM + tn * 256 + wc * 64 + lc;
            out[rb]      = (float)acc[mi][0][reg] * s;
            out[rb + 32] = (float)acc[mi][1][reg] * s;
        }
    }
}

extern "C" void kernel_launch(void* const* d_in, const int* in_sizes, int n_in,
                              void* d_out, int out_size, void* d_ws, size_t ws_size,
                              hipStream_t stream) {
    const float* x  = (const float*)d_in[0];   // [4,2048,2048]
    const float* wt = (const float*)d_in[1];   // [8192,2048]
    float* out = (float*)d_out;                // [4,2048,8192] fp32

    char* ws = (char*)d_ws;
    uint8_t* xq     = (uint8_t*)ws;                     // 16,777,216 B
    uint8_t* wq     = (uint8_t*)(ws + 16777216);        // 16,777,216 B
    float* alpha    = (float*)(ws + 33554432);          // 32,768 B
    float* partial  = (float*)(ws + 33587200);          // 8,192 B
    float* gamma    = (float*)(ws + 33595392);          // 4 B

    k_abs_partial<<<2048, 256, 0, stream>>>(wt, partial);
    k_gamma<<<1, 256, 0, stream>>>(partial, gamma);
    k_quant_w<<<16384, 256, 0, stream>>>(wt, gamma, (uint*)wq);
    k_quant_x<<<8192, 256, 0, stream>>>(x, (uint*)xq, alpha);
    k_gemm<<<1024, 512, 0, stream>>>(xq, wq, alpha, gamma, out);
}